// Round 3
// baseline (351.132 us; speedup 1.0000x reference)
//
#include <hip/hip_runtime.h>
#include <hip/hip_bf16.h>

// CausalAttention: B=4, S=2048, d=1024, single head, causal.
// I/O dtype: fp32 (per reference). Internal compute: bf16 MFMA, fp32 accum.
//
// Pipeline:
//   1) Wq/Wk/Wv fp32 -> bf16 transposed Wt      (projections become NT gemms)
//   2) x fp32 -> bf16 Xb
//   3) Q = Xb*Wq, K = Xb*Wk, V = Xb*Wv          (bf16 NT gemms)
//   4) Vt = V^T per batch
//   5) Sc = Q*K^T per batch (skip fully-masked upper-triangle 128x128 tiles)
//   6) causal softmax rows of Sc in place (mask-before-scale == softmax(s/32) on valid cols)
//   7) out(fp32) = P * V  (NT with Vt; K-loop clamped to rowBase+128: causal zeros beyond)
//
// ws reuse: Sc (33.55 MB) aliases [Xb|V] (33.55 MB) -- both dead before Sc gemm.

typedef __bf16 bf16_t;
typedef __bf16 bf16x8 __attribute__((ext_vector_type(8)));
typedef float f32x4 __attribute__((ext_vector_type(4)));

#define BM 128
#define BN 128
#define BK 32

// C[m][n] = sum_k A[m][k] * B[n][k]   (A:[M][K], B:[N][K] row-major bf16; C:[M][N] OT)
// mode: 0 dense | 1 scores (skip tiles fully above diagonal) | 2 pv (clamp K at rowBase+BM)
template <typename OT>
__global__ __launch_bounds__(256)
void gemm_nt_bf16(const bf16_t* __restrict__ A, const bf16_t* __restrict__ B,
                  OT* __restrict__ C,
                  int M, int N, int K,
                  long strideA, long strideB, long strideC, int mode)
{
  const int rowBase = blockIdx.y * BM;
  const int colBase = blockIdx.x * BN;
  if (mode == 1 && colBase >= rowBase + BM) return;  // fully-masked score tile

  __shared__ __align__(16) bf16_t sA[BM * BK];   // [row][k], 8 KB
  __shared__ __align__(16) bf16_t sB[BN * BK];   // [n][k],   8 KB

  A += (size_t)blockIdx.z * strideA;
  B += (size_t)blockIdx.z * strideB;
  C += (size_t)blockIdx.z * strideC;

  const int tid  = threadIdx.x;
  const int wave = tid >> 6;
  const int lane = tid & 63;
  const int quad = lane >> 4;
  const int ln16 = lane & 15;

  const int wm = (wave & 1) * 64;   // wave's 64x64 subtile of the 128x128 block
  const int wn = (wave >> 1) * 64;

  // cooperative staging: 256 threads x 8 elem = half a 128x32 tile per shot
  const int tRow = tid >> 2;         // 0..63
  const int tCol = (tid & 3) * 8;    // 0,8,16,24

  f32x4 acc[4][4] = {};

  const int Kend = (mode == 2) ? (K < rowBase + BM ? K : rowBase + BM) : K;

  for (int k0 = 0; k0 < Kend; k0 += BK) {
    const bf16_t* pa = A + (size_t)(rowBase + tRow) * K + (k0 + tCol);
    const bf16_t* pb = B + (size_t)(colBase + tRow) * K + (k0 + tCol);
    bf16x8 a0 = *(const bf16x8*)pa;
    bf16x8 a1 = *(const bf16x8*)(pa + (size_t)64 * K);
    bf16x8 b0 = *(const bf16x8*)pb;
    bf16x8 b1 = *(const bf16x8*)(pb + (size_t)64 * K);
    *(bf16x8*)(sA + tRow * BK + tCol)        = a0;
    *(bf16x8*)(sA + (tRow + 64) * BK + tCol) = a1;
    *(bf16x8*)(sB + tRow * BK + tCol)        = b0;
    *(bf16x8*)(sB + (tRow + 64) * BK + tCol) = b1;
    __syncthreads();

    bf16x8 af[4], bfr[4];
#pragma unroll
    for (int mt = 0; mt < 4; mt++)
      af[mt] = *(const bf16x8*)(sA + (wm + mt * 16 + ln16) * BK + quad * 8);
#pragma unroll
    for (int nt = 0; nt < 4; nt++)
      bfr[nt] = *(const bf16x8*)(sB + (wn + nt * 16 + ln16) * BK + quad * 8);
#pragma unroll
    for (int mt = 0; mt < 4; mt++)
#pragma unroll
      for (int nt = 0; nt < 4; nt++)
        acc[mt][nt] = __builtin_amdgcn_mfma_f32_16x16x32_bf16(af[mt], bfr[nt], acc[mt][nt], 0, 0, 0);
    __syncthreads();
  }

  // epilogue: C/D layout col = lane&15, row = quad*4 + r  [measured m89/m91]
#pragma unroll
  for (int mt = 0; mt < 4; mt++) {
#pragma unroll
    for (int nt = 0; nt < 4; nt++) {
#pragma unroll
      for (int r = 0; r < 4; r++) {
        const int row = rowBase + wm + mt * 16 + quad * 4 + r;
        const int col = colBase + wn + nt * 16 + ln16;
        C[(size_t)row * N + col] = (OT)acc[mt][nt][r];
      }
    }
  }
}

// fp32 [R][C] -> bf16 transposed [C][R]
__global__ __launch_bounds__(256)
void transpose_cvt_f32_bf16(const float* __restrict__ in, bf16_t* __restrict__ out,
                            int R, int C)
{
  __shared__ float tile[32][33];
  const int c0 = blockIdx.x * 32, r0 = blockIdx.y * 32;
  const int tx = threadIdx.x, ty = threadIdx.y;  // (32, 8)
#pragma unroll
  for (int i = 0; i < 32; i += 8)
    tile[ty + i][tx] = in[(size_t)(r0 + ty + i) * C + (c0 + tx)];
  __syncthreads();
#pragma unroll
  for (int i = 0; i < 32; i += 8)
    out[(size_t)(c0 + ty + i) * R + (r0 + tx)] = (bf16_t)tile[tx][ty + i];
}

// bf16 [R][C] -> bf16 transposed [C][R]; batched via blockIdx.z
__global__ __launch_bounds__(256)
void transpose16(const unsigned short* __restrict__ in, unsigned short* __restrict__ out,
                 int R, int C)
{
  __shared__ unsigned short tile[32][33];
  const size_t bo = (size_t)blockIdx.z * R * C;
  const int c0 = blockIdx.x * 32, r0 = blockIdx.y * 32;
  const int tx = threadIdx.x, ty = threadIdx.y;  // (32, 8)
#pragma unroll
  for (int i = 0; i < 32; i += 8)
    tile[ty + i][tx] = in[bo + (size_t)(r0 + ty + i) * C + (c0 + tx)];
  __syncthreads();
#pragma unroll
  for (int i = 0; i < 32; i += 8)
    out[bo + (size_t)(c0 + ty + i) * R + (r0 + tx)] = tile[tx][ty + i];
}

// fp32 -> bf16 elementwise, 4 elems/thread
__global__ __launch_bounds__(256)
void cvt_f32_bf16(const float* __restrict__ in, bf16_t* __restrict__ out, long n)
{
  long i = ((long)blockIdx.x * 256 + threadIdx.x) * 4;
  if (i + 3 < n) {
    float4 v = *(const float4*)(in + i);
    out[i + 0] = (bf16_t)v.x;
    out[i + 1] = (bf16_t)v.y;
    out[i + 2] = (bf16_t)v.z;
    out[i + 3] = (bf16_t)v.w;
  }
}

// In-place causal softmax on bf16 scores [B*S][S]; row q valid cols 0..q.
__global__ __launch_bounds__(256)
void softmax_causal(bf16_t* __restrict__ sc, int S)
{
  const int row = blockIdx.x;        // b*S + q
  const int q   = row & (S - 1);
  bf16_t* r = sc + (size_t)row * S;
  const int tid = threadIdx.x;
  const int nvalid = q + 1;
  constexpr float inv = 0.03125f;    // 1/sqrt(1024)

  __shared__ float sred[4];
  __shared__ float sbc[2];

  float lmax = -3.0e38f;
  for (int c = tid; c < nvalid; c += 256) lmax = fmaxf(lmax, (float)r[c]);
#pragma unroll
  for (int off = 32; off > 0; off >>= 1) lmax = fmaxf(lmax, __shfl_down(lmax, off, 64));
  if ((tid & 63) == 0) sred[tid >> 6] = lmax;
  __syncthreads();
  if (tid == 0) sbc[0] = fmaxf(fmaxf(sred[0], sred[1]), fmaxf(sred[2], sred[3]));
  __syncthreads();
  const float rmax = sbc[0];

  float lsum = 0.0f;
  for (int c = tid; c < nvalid; c += 256) lsum += __expf(((float)r[c] - rmax) * inv);
#pragma unroll
  for (int off = 32; off > 0; off >>= 1) lsum += __shfl_down(lsum, off, 64);
  if ((tid & 63) == 0) sred[tid >> 6] = lsum;
  __syncthreads();
  if (tid == 0) sbc[1] = sred[0] + sred[1] + sred[2] + sred[3];
  __syncthreads();
  const float rinv = 1.0f / fmaxf(sbc[1], 1e-30f);

  for (int c = tid; c < S; c += 256) {
    float p = 0.0f;
    if (c < nvalid) p = __expf(((float)r[c] - rmax) * inv) * rinv;
    r[c] = (bf16_t)p;
  }
}

extern "C" void kernel_launch(void* const* d_in, const int* in_sizes, int n_in,
                              void* d_out, int out_size, void* d_ws, size_t ws_size,
                              hipStream_t stream) {
  const float* x  = (const float*)d_in[0];
  const float* Wq = (const float*)d_in[1];
  const float* Wk = (const float*)d_in[2];
  const float* Wv = (const float*)d_in[3];
  float* out = (float*)d_out;

  const int Bb = 4, S = 2048, D = 1024;
  const int M = Bb * S;  // 8192

  // ws layout (bf16 elems): Q | K | Vt | Wt(x3) | SHARED(2*M*D)  = 90,177,536 B
  // SHARED holds Xb (first M*D) and V (second M*D); Sc aliases all of SHARED.
  bf16_t* ws = (bf16_t*)d_ws;
  bf16_t* Q   = ws;                          // M*D
  bf16_t* Kp  = Q  + (size_t)M * D;          // M*D
  bf16_t* Vt  = Kp + (size_t)M * D;          // M*D   ([D][S] per batch)
  bf16_t* Wt  = Vt + (size_t)M * D;          // 3*D*D
  bf16_t* Xb  = Wt + 3 * (size_t)D * D;      // M*D
  bf16_t* V   = Xb + (size_t)M * D;          // M*D
  bf16_t* Sc  = Xb;                          // Bb*S*S  (== 2*M*D, aliases Xb|V)

  const dim3 tb(32, 8);
  const dim3 blk(256);

  // 1) W fp32 -> bf16 transposed
  transpose_cvt_f32_bf16<<<dim3(D / 32, D / 32), tb, 0, stream>>>(Wq, Wt, D, D);
  transpose_cvt_f32_bf16<<<dim3(D / 32, D / 32), tb, 0, stream>>>(Wk, Wt + (size_t)D * D, D, D);
  transpose_cvt_f32_bf16<<<dim3(D / 32, D / 32), tb, 0, stream>>>(Wv, Wt + 2 * (size_t)D * D, D, D);

  // 2) x fp32 -> bf16
  cvt_f32_bf16<<<dim3((M * D) / (256 * 4)), blk, 0, stream>>>(x, Xb, (long)M * D);

  // 3) projections
  gemm_nt_bf16<bf16_t><<<dim3(D / BN, M / BM, 1), blk, 0, stream>>>(Xb, Wt,                     Q,  M, D, D, 0, 0, 0, 0);
  gemm_nt_bf16<bf16_t><<<dim3(D / BN, M / BM, 1), blk, 0, stream>>>(Xb, Wt + (size_t)D * D,     Kp, M, D, D, 0, 0, 0, 0);
  gemm_nt_bf16<bf16_t><<<dim3(D / BN, M / BM, 1), blk, 0, stream>>>(Xb, Wt + 2 * (size_t)D * D, V,  M, D, D, 0, 0, 0, 0);

  // 4) V transpose per batch
  transpose16<<<dim3(D / 32, S / 32, Bb), tb, 0, stream>>>((const unsigned short*)V, (unsigned short*)Vt, S, D);

  // 5) scores Sc = Q * K^T per batch (upper-triangle tiles skipped; Xb/V dead now)
  gemm_nt_bf16<bf16_t><<<dim3(S / BN, S / BM, Bb), blk, 0, stream>>>(Q, Kp, Sc, S, S, D,
                                                                     (long)S * D, (long)S * D, (long)S * S, 1);

  // 6) causal softmax in place (also zeroes the skipped upper-triangle region)
  softmax_causal<<<dim3(Bb * S), blk, 0, stream>>>(Sc, S);

  // 7) out(fp32) = P * V  (NT with Vt; K clamped causally)
  gemm_nt_bf16<float><<<dim3(D / BN, S / BM, Bb), blk, 0, stream>>>(Sc, Vt, out, S, D, S,
                                                                    (long)S * S, (long)D * S, (long)S * D, 2);
}

// Round 4
// 310.522 us; speedup vs baseline: 1.1308x; 1.1308x over previous
//
#include <hip/hip_runtime.h>
#include <hip/hip_bf16.h>

// CausalAttention: B=4, S=2048, d=1024, single head, causal. fp32 I/O, bf16 MFMA inside.
//
// R4: (1) async global_load_lds width-16 staging (m97 recipe) restored;
//     (2) Q/K/V projections fused into one N=3072 GEMM (epilogue splits outputs);
//     (3) softmax writes stop at the causal 128-block edge.
//
// Pipeline:
//   1) Wq/Wk/Wv fp32 -> bf16 transposed, stacked Wt [3072][1024]
//   2) x fp32 -> bf16 Xb
//   3) {Q,K,V} = Xb * Wt^T  (one fused NT gemm, mode 3)
//   4) Vt = V^T per batch
//   5) Sc = Q*K^T per batch (skip tiles fully above diagonal, mode 1)
//   6) causal softmax rows of Sc in place (mask-before-scale == softmax(s/32))
//   7) out(fp32) = P*V  (NT with Vt; K clamped at rowBase+128, mode 2)

typedef __bf16 bf16_t;
typedef __bf16 bf16x8 __attribute__((ext_vector_type(8)));
typedef float f32x4 __attribute__((ext_vector_type(4)));

#define BM 128
#define BN 128
#define BK 32

__device__ __forceinline__ void load_lds16(const bf16_t* g, bf16_t* l) {
  __builtin_amdgcn_global_load_lds(
      (__attribute__((address_space(1))) void*)(void*)g,
      (__attribute__((address_space(3))) void*)l,
      16, 0, 0);
}

// C[m][n] = sum_k A[m][k]*B[n][k]  (A:[M][K], B:[N][K] row-major bf16)
// mode: 0 dense | 1 scores (skip tiles fully above diag) | 2 pv (clamp K at rowBase+BM)
//       3 fused qkv (block col / 1024 selects C0/C1/C2, ldc=1024)
template <typename OT>
__global__ __launch_bounds__(256)
void gemm_nt_bf16(const bf16_t* __restrict__ A, const bf16_t* __restrict__ B,
                  OT* __restrict__ C0, OT* __restrict__ C1, OT* __restrict__ C2,
                  int M, int K, int ldc,
                  long strideA, long strideB, long strideC, int mode)
{
  const int rowBase = blockIdx.y * BM;
  const int colBase = blockIdx.x * BN;
  if (mode == 1 && colBase >= rowBase + BM) return;  // fully-masked score tile

  __shared__ __align__(16) bf16_t sA[BM * BK];   // [row][k], 8 KB
  __shared__ __align__(16) bf16_t sB[BN * BK];   // [n][k],   8 KB

  A += (size_t)blockIdx.z * strideA;
  B += (size_t)blockIdx.z * strideB;

  const int tid  = threadIdx.x;
  const int wave = tid >> 6;
  const int lane = tid & 63;
  const int quad = lane >> 4;
  const int ln16 = lane & 15;

  const int wm = (wave & 1) * 64;   // wave's 64x64 subtile
  const int wn = (wave >> 1) * 64;

  // async staging: each wave stages 2 chunks of A-tile and B-tile;
  // chunk = 64 lanes x 16B, LDS dest = wave-uniform base + lane*16B (elems: wave*1024 + 8*lane)
  const int sRow = wave * 32 + (lane >> 2);
  const int sCol = (lane & 3) * 8;
  bf16_t* ldsA = sA + wave * 1024;
  bf16_t* ldsB = sB + wave * 1024;

  f32x4 acc[4][4] = {};

  const int Kend = (mode == 2) ? (K < rowBase + BM ? K : rowBase + BM) : K;

  for (int k0 = 0; k0 < Kend; k0 += BK) {
    const bf16_t* pa = A + (size_t)(rowBase + sRow) * K + (k0 + sCol);
    const bf16_t* pb = B + (size_t)(colBase + sRow) * K + (k0 + sCol);
    load_lds16(pa,                  ldsA);
    load_lds16(pa + (size_t)16 * K, ldsA + 512);
    load_lds16(pb,                  ldsB);
    load_lds16(pb + (size_t)16 * K, ldsB + 512);
    __syncthreads();   // drains vmcnt (global_load_lds) for all waves

    bf16x8 af[4], bfr[4];
#pragma unroll
    for (int mt = 0; mt < 4; mt++)
      af[mt] = *(const bf16x8*)(sA + (wm + mt * 16 + ln16) * BK + quad * 8);
#pragma unroll
    for (int nt = 0; nt < 4; nt++)
      bfr[nt] = *(const bf16x8*)(sB + (wn + nt * 16 + ln16) * BK + quad * 8);
#pragma unroll
    for (int mt = 0; mt < 4; mt++)
#pragma unroll
      for (int nt = 0; nt < 4; nt++)
        acc[mt][nt] = __builtin_amdgcn_mfma_f32_16x16x32_bf16(af[mt], bfr[nt], acc[mt][nt], 0, 0, 0);
    __syncthreads();
  }

  // output target: mode 3 splits by 1024-col groups (uniform per block)
  OT* Cw = C0;
  int cb = colBase;
  if (mode == 3) {
    const int which = colBase >> 10;
    Cw = (which == 0) ? C0 : (which == 1) ? C1 : C2;
    cb = colBase & 1023;
  }
  Cw += (size_t)blockIdx.z * strideC;

  // epilogue: C/D layout col = lane&15, row = quad*4 + r  [measured m89/m91]
#pragma unroll
  for (int mt = 0; mt < 4; mt++) {
#pragma unroll
    for (int nt = 0; nt < 4; nt++) {
#pragma unroll
      for (int r = 0; r < 4; r++) {
        const int row = rowBase + wm + mt * 16 + quad * 4 + r;
        const int col = cb + wn + nt * 16 + ln16;
        Cw[(size_t)row * ldc + col] = (OT)acc[mt][nt][r];
      }
    }
  }
}

// fp32 [R][C] -> bf16 transposed [C][R]
__global__ __launch_bounds__(256)
void transpose_cvt_f32_bf16(const float* __restrict__ in, bf16_t* __restrict__ out,
                            int R, int C)
{
  __shared__ float tile[32][33];
  const int c0 = blockIdx.x * 32, r0 = blockIdx.y * 32;
  const int tx = threadIdx.x, ty = threadIdx.y;  // (32, 8)
#pragma unroll
  for (int i = 0; i < 32; i += 8)
    tile[ty + i][tx] = in[(size_t)(r0 + ty + i) * C + (c0 + tx)];
  __syncthreads();
#pragma unroll
  for (int i = 0; i < 32; i += 8)
    out[(size_t)(c0 + ty + i) * R + (r0 + tx)] = (bf16_t)tile[tx][ty + i];
}

// bf16 [R][C] -> bf16 transposed [C][R]; batched via blockIdx.z
__global__ __launch_bounds__(256)
void transpose16(const unsigned short* __restrict__ in, unsigned short* __restrict__ out,
                 int R, int C)
{
  __shared__ unsigned short tile[32][33];
  const size_t bo = (size_t)blockIdx.z * R * C;
  const int c0 = blockIdx.x * 32, r0 = blockIdx.y * 32;
  const int tx = threadIdx.x, ty = threadIdx.y;  // (32, 8)
#pragma unroll
  for (int i = 0; i < 32; i += 8)
    tile[ty + i][tx] = in[bo + (size_t)(r0 + ty + i) * C + (c0 + tx)];
  __syncthreads();
#pragma unroll
  for (int i = 0; i < 32; i += 8)
    out[bo + (size_t)(c0 + ty + i) * R + (r0 + tx)] = tile[tx][ty + i];
}

// fp32 -> bf16 elementwise, 4/thread
__global__ __launch_bounds__(256)
void cvt_f32_bf16(const float* __restrict__ in, bf16_t* __restrict__ out, long n)
{
  long i = ((long)blockIdx.x * 256 + threadIdx.x) * 4;
  if (i + 3 < n) {
    float4 v = *(const float4*)(in + i);
    out[i + 0] = (bf16_t)v.x;
    out[i + 1] = (bf16_t)v.y;
    out[i + 2] = (bf16_t)v.z;
    out[i + 3] = (bf16_t)v.w;
  }
}

// In-place causal softmax on bf16 scores [B*S][S]; row q valid cols 0..q.
// Zeros only up to the causal 128-block edge -- PV's K-clamp never reads beyond.
__global__ __launch_bounds__(256)
void softmax_causal(bf16_t* __restrict__ sc, int S)
{
  const int row = blockIdx.x;        // b*S + q
  const int q   = row & (S - 1);
  bf16_t* r = sc + (size_t)row * S;
  const int tid = threadIdx.x;
  const int nvalid = q + 1;
  const int wend = ((q >> 7) + 1) << 7;   // 128-aligned end of writes
  constexpr float inv = 0.03125f;    // 1/sqrt(1024)

  __shared__ float sred[4];
  __shared__ float sbc[2];

  float lmax = -3.0e38f;
  for (int c = tid; c < nvalid; c += 256) lmax = fmaxf(lmax, (float)r[c]);
#pragma unroll
  for (int off = 32; off > 0; off >>= 1) lmax = fmaxf(lmax, __shfl_down(lmax, off, 64));
  if ((tid & 63) == 0) sred[tid >> 6] = lmax;
  __syncthreads();
  if (tid == 0) sbc[0] = fmaxf(fmaxf(sred[0], sred[1]), fmaxf(sred[2], sred[3]));
  __syncthreads();
  const float rmax = sbc[0];

  float lsum = 0.0f;
  for (int c = tid; c < nvalid; c += 256) lsum += __expf(((float)r[c] - rmax) * inv);
#pragma unroll
  for (int off = 32; off > 0; off >>= 1) lsum += __shfl_down(lsum, off, 64);
  if ((tid & 63) == 0) sred[tid >> 6] = lsum;
  __syncthreads();
  if (tid == 0) sbc[1] = sred[0] + sred[1] + sred[2] + sred[3];
  __syncthreads();
  const float rinv = 1.0f / fmaxf(sbc[1], 1e-30f);

  for (int c = tid; c < wend; c += 256) {
    float p = 0.0f;
    if (c < nvalid) p = __expf(((float)r[c] - rmax) * inv) * rinv;
    r[c] = (bf16_t)p;
  }
}

extern "C" void kernel_launch(void* const* d_in, const int* in_sizes, int n_in,
                              void* d_out, int out_size, void* d_ws, size_t ws_size,
                              hipStream_t stream) {
  const float* x  = (const float*)d_in[0];
  const float* Wq = (const float*)d_in[1];
  const float* Wk = (const float*)d_in[2];
  const float* Wv = (const float*)d_in[3];
  float* out = (float*)d_out;

  const int Bb = 4, S = 2048, D = 1024;
  const int M = Bb * S;  // 8192

  // ws (bf16 elems): Q | K | Vt | Wt(3*D*D) | Xb | V   = 90,177,536 B (proven fit)
  // Sc (Bb*S*S == 2*M*D) aliases [Xb|V], both dead before the scores gemm.
  bf16_t* ws = (bf16_t*)d_ws;
  bf16_t* Q   = ws;
  bf16_t* Kp  = Q  + (size_t)M * D;
  bf16_t* Vt  = Kp + (size_t)M * D;
  bf16_t* Wt  = Vt + (size_t)M * D;          // [3072][1024] stacked
  bf16_t* Xb  = Wt + 3 * (size_t)D * D;
  bf16_t* V   = Xb + (size_t)M * D;
  bf16_t* Sc  = Xb;

  const dim3 tb(32, 8);
  const dim3 blk(256);

  // 1) W fp32 -> bf16 transposed, stacked
  transpose_cvt_f32_bf16<<<dim3(D / 32, D / 32), tb, 0, stream>>>(Wq, Wt, D, D);
  transpose_cvt_f32_bf16<<<dim3(D / 32, D / 32), tb, 0, stream>>>(Wk, Wt + (size_t)D * D, D, D);
  transpose_cvt_f32_bf16<<<dim3(D / 32, D / 32), tb, 0, stream>>>(Wv, Wt + 2 * (size_t)D * D, D, D);

  // 2) x -> bf16
  cvt_f32_bf16<<<dim3((M * D) / (256 * 4)), blk, 0, stream>>>(x, Xb, (long)M * D);

  // 3) fused projections: {Q,K,V} = Xb * Wt^T   (grid 24 x 64 = 1536 blocks)
  gemm_nt_bf16<bf16_t><<<dim3(3 * D / BN, M / BM, 1), blk, 0, stream>>>(
      Xb, Wt, Q, Kp, V, M, D, D, 0, 0, 0, 3);

  // 4) Vt per batch
  transpose16<<<dim3(D / 32, S / 32, Bb), tb, 0, stream>>>((const unsigned short*)V, (unsigned short*)Vt, S, D);

  // 5) scores Sc = Q*K^T per batch (upper-triangle tiles skipped; Xb/V dead)
  gemm_nt_bf16<bf16_t><<<dim3(S / BN, S / BM, Bb), blk, 0, stream>>>(
      Q, Kp, Sc, Sc, Sc, S, D, S, (long)S * D, (long)S * D, (long)S * S, 1);

  // 6) causal softmax in place
  softmax_causal<<<dim3(Bb * S), blk, 0, stream>>>(Sc, S);

  // 7) out(fp32) = P*V  (NT with Vt; K clamped causally)
  gemm_nt_bf16<float><<<dim3(D / BN, S / BM, Bb), blk, 0, stream>>>(
      Sc, Vt, out, out, out, S, S, D, (long)S * S, (long)D * S, (long)S * D, 2);
}

// Round 5
// 290.721 us; speedup vs baseline: 1.2078x; 1.0681x over previous
//
#include <hip/hip_runtime.h>
#include <hip/hip_bf16.h>

// CausalAttention: B=4, S=2048, d=1024, single head, causal. fp32 I/O, bf16 MFMA inside.
//
// R5: (1) XOR bank-swizzle on LDS chunk placement (kills 8-way ds_read_b128 conflicts;
//         staging permutes WHICH global chunk each lane fetches since global_load_lds
//         LDS dest is fixed at base+lane*16);
//     (2) softmax: one bf16x8 load/thread, values held in registers across max/sum/store;
//     (3) W transposes merged into one launch; cvt vector stores.
//
// Pipeline:
//   1) Wq/Wk/Wv fp32 -> bf16 transposed, stacked Wt [3072][1024]   (one launch)
//   2) x fp32 -> bf16 Xb
//   3) {Q,K,V} = Xb * Wt^T  (one fused NT gemm, mode 3)
//   4) Vt = V^T per batch
//   5) Sc = Q*K^T per batch (skip tiles fully above diagonal, mode 1)
//   6) causal softmax rows of Sc in place (mask-before-scale == softmax(s/32))
//   7) out(fp32) = P*V  (NT with Vt; K clamped at rowBase+128, mode 2)

typedef __bf16 bf16_t;
typedef __bf16 bf16x8 __attribute__((ext_vector_type(8)));
typedef float f32x4 __attribute__((ext_vector_type(4)));

#define BM 128
#define BN 128
#define BK 32

__device__ __forceinline__ void load_lds16(const bf16_t* g, bf16_t* l) {
  __builtin_amdgcn_global_load_lds(
      (__attribute__((address_space(1))) void*)(void*)g,
      (__attribute__((address_space(3))) void*)l,
      16, 0, 0);
}

// C[m][n] = sum_k A[m][k]*B[n][k]  (A:[M][K], B:[N][K] row-major bf16)
// mode: 0 dense | 1 scores (skip tiles fully above diag) | 2 pv (clamp K at rowBase+BM)
//       3 fused qkv (block col / 1024 selects C0/C1/C2, ldc=1024)
// LDS layout swizzle: 16B chunk (row, c') holds global chunk (row, c'^((row>>1)&3)).
// Fragment read of (row, quad) therefore reads chunk quad^((row>>1)&3); bank position
// key (row&1, chunk) then covers all 8 positions 2-way across a quad's 16 lanes (free).
template <typename OT>
__global__ __launch_bounds__(256)
void gemm_nt_bf16(const bf16_t* __restrict__ A, const bf16_t* __restrict__ B,
                  OT* __restrict__ C0, OT* __restrict__ C1, OT* __restrict__ C2,
                  int M, int K, int ldc,
                  long strideA, long strideB, long strideC, int mode)
{
  const int rowBase = blockIdx.y * BM;
  const int colBase = blockIdx.x * BN;
  if (mode == 1 && colBase >= rowBase + BM) return;  // fully-masked score tile

  __shared__ __align__(16) bf16_t sA[BM * BK];   // [row][k], 8 KB
  __shared__ __align__(16) bf16_t sB[BN * BK];   // [n][k],   8 KB

  A += (size_t)blockIdx.z * strideA;
  B += (size_t)blockIdx.z * strideB;

  const int tid  = threadIdx.x;
  const int wave = tid >> 6;
  const int lane = tid & 63;
  const int quad = lane >> 4;
  const int ln16 = lane & 15;

  const int wm = (wave & 1) * 64;   // wave's 64x64 subtile
  const int wn = (wave >> 1) * 64;

  // staging: wave stages rows [wave*32, wave*32+16) x2; lane ell -> LDS chunk
  // (r = ell>>2, c' = ell&3); fetch global chunk c = c' ^ swz(r). swz(r+16)==swz(r).
  const int sRow = wave * 32 + (lane >> 2);
  const int sCol = (((lane & 3) ^ ((sRow >> 1) & 3)) * 8);
  bf16_t* ldsA = sA + wave * 1024;
  bf16_t* ldsB = sB + wave * 1024;

  f32x4 acc[4][4] = {};

  const int Kend = (mode == 2) ? (K < rowBase + BM ? K : rowBase + BM) : K;

  for (int k0 = 0; k0 < Kend; k0 += BK) {
    const bf16_t* pa = A + (size_t)(rowBase + sRow) * K + (k0 + sCol);
    const bf16_t* pb = B + (size_t)(colBase + sRow) * K + (k0 + sCol);
    load_lds16(pa,                  ldsA);
    load_lds16(pa + (size_t)16 * K, ldsA + 512);
    load_lds16(pb,                  ldsB);
    load_lds16(pb + (size_t)16 * K, ldsB + 512);
    __syncthreads();   // drains vmcnt for all waves

    bf16x8 af[4], bfr[4];
#pragma unroll
    for (int mt = 0; mt < 4; mt++) {
      const int row = wm + mt * 16 + ln16;
      af[mt] = *(const bf16x8*)(sA + row * BK + (quad ^ ((row >> 1) & 3)) * 8);
    }
#pragma unroll
    for (int nt = 0; nt < 4; nt++) {
      const int row = wn + nt * 16 + ln16;
      bfr[nt] = *(const bf16x8*)(sB + row * BK + (quad ^ ((row >> 1) & 3)) * 8);
    }
#pragma unroll
    for (int mt = 0; mt < 4; mt++)
#pragma unroll
      for (int nt = 0; nt < 4; nt++)
        acc[mt][nt] = __builtin_amdgcn_mfma_f32_16x16x32_bf16(af[mt], bfr[nt], acc[mt][nt], 0, 0, 0);
    __syncthreads();
  }

  // output target: mode 3 splits by 1024-col groups (uniform per block)
  OT* Cw = C0;
  int cb = colBase;
  if (mode == 3) {
    const int which = colBase >> 10;
    Cw = (which == 0) ? C0 : (which == 1) ? C1 : C2;
    cb = colBase & 1023;
  }
  Cw += (size_t)blockIdx.z * strideC;

  // epilogue: C/D layout col = lane&15, row = quad*4 + r  [measured m89/m91]
#pragma unroll
  for (int mt = 0; mt < 4; mt++) {
#pragma unroll
    for (int nt = 0; nt < 4; nt++) {
#pragma unroll
      for (int r = 0; r < 4; r++) {
        const int row = rowBase + wm + mt * 16 + quad * 4 + r;
        const int col = cb + wn + nt * 16 + ln16;
        Cw[(size_t)row * ldc + col] = (OT)acc[mt][nt][r];
      }
    }
  }
}

// three fp32 [D][D] -> bf16 transposed, stacked [3D][D]; z selects source
__global__ __launch_bounds__(256)
void transpose_cvt3(const float* __restrict__ w0, const float* __restrict__ w1,
                    const float* __restrict__ w2, bf16_t* __restrict__ out, int D)
{
  const float* in = (blockIdx.z == 0) ? w0 : (blockIdx.z == 1) ? w1 : w2;
  bf16_t* o = out + (size_t)blockIdx.z * D * D;
  __shared__ float tile[32][33];
  const int c0 = blockIdx.x * 32, r0 = blockIdx.y * 32;
  const int tx = threadIdx.x, ty = threadIdx.y;  // (32, 8)
#pragma unroll
  for (int i = 0; i < 32; i += 8)
    tile[ty + i][tx] = in[(size_t)(r0 + ty + i) * D + (c0 + tx)];
  __syncthreads();
#pragma unroll
  for (int i = 0; i < 32; i += 8)
    o[(size_t)(c0 + ty + i) * D + (r0 + tx)] = (bf16_t)tile[tx][ty + i];
}

// bf16 [R][C] -> bf16 transposed [C][R]; batched via blockIdx.z
__global__ __launch_bounds__(256)
void transpose16(const unsigned short* __restrict__ in, unsigned short* __restrict__ out,
                 int R, int C)
{
  __shared__ unsigned short tile[32][33];
  const size_t bo = (size_t)blockIdx.z * R * C;
  const int c0 = blockIdx.x * 32, r0 = blockIdx.y * 32;
  const int tx = threadIdx.x, ty = threadIdx.y;  // (32, 8)
#pragma unroll
  for (int i = 0; i < 32; i += 8)
    tile[ty + i][tx] = in[bo + (size_t)(r0 + ty + i) * C + (c0 + tx)];
  __syncthreads();
#pragma unroll
  for (int i = 0; i < 32; i += 8)
    out[bo + (size_t)(c0 + ty + i) * R + (r0 + tx)] = tile[tx][ty + i];
}

// fp32 -> bf16 elementwise, 8/thread, vector load+store
__global__ __launch_bounds__(256)
void cvt_f32_bf16(const float* __restrict__ in, bf16_t* __restrict__ out, long n)
{
  long i = ((long)blockIdx.x * 256 + threadIdx.x) * 8;
  if (i + 7 < n) {
    float4 a = *(const float4*)(in + i);
    float4 b = *(const float4*)(in + i + 4);
    bf16x8 o;
    o[0] = (bf16_t)a.x; o[1] = (bf16_t)a.y; o[2] = (bf16_t)a.z; o[3] = (bf16_t)a.w;
    o[4] = (bf16_t)b.x; o[5] = (bf16_t)b.y; o[6] = (bf16_t)b.z; o[7] = (bf16_t)b.w;
    *(bf16x8*)(out + i) = o;
  }
}

// In-place causal softmax on bf16 scores [B*S][S]; row q valid cols 0..q.
// One bf16x8 per thread (S=2048=256*8): single read, values live in registers.
// Writes only to the causal 128-block edge (PV's K-clamp never reads beyond).
__global__ __launch_bounds__(256)
void softmax_causal(bf16_t* __restrict__ sc, int S)
{
  const int row = blockIdx.x;        // b*S + q
  const int q   = row & (S - 1);
  bf16_t* r = sc + (size_t)row * S;
  const int tid = threadIdx.x;
  const int nvalid = q + 1;
  const int wend = ((q >> 7) + 1) << 7;   // 128-aligned write end
  constexpr float inv = 0.03125f;         // 1/sqrt(1024)
  const int base = tid * 8;

  __shared__ float sred[4];
  __shared__ float sbc[2];

  float v[8];
  const bool inw = base < wend;
  if (inw) {
    bf16x8 d = *(const bf16x8*)(r + base);
#pragma unroll
    for (int j = 0; j < 8; j++) v[j] = (float)d[j];
  }

  float lmax = -3.0e38f;
  if (base < nvalid) {
#pragma unroll
    for (int j = 0; j < 8; j++) if (base + j < nvalid) lmax = fmaxf(lmax, v[j]);
  }
#pragma unroll
  for (int off = 32; off > 0; off >>= 1) lmax = fmaxf(lmax, __shfl_down(lmax, off, 64));
  if ((tid & 63) == 0) sred[tid >> 6] = lmax;
  __syncthreads();
  if (tid == 0) sbc[0] = fmaxf(fmaxf(sred[0], sred[1]), fmaxf(sred[2], sred[3]));
  __syncthreads();
  const float rmax = sbc[0];

  float e[8];
  float lsum = 0.0f;
#pragma unroll
  for (int j = 0; j < 8; j++) {
    if (base + j < nvalid) { e[j] = __expf((v[j] - rmax) * inv); lsum += e[j]; }
    else e[j] = 0.0f;
  }
#pragma unroll
  for (int off = 32; off > 0; off >>= 1) lsum += __shfl_down(lsum, off, 64);
  if ((tid & 63) == 0) sred[tid >> 6] = lsum;
  __syncthreads();
  if (tid == 0) sbc[1] = sred[0] + sred[1] + sred[2] + sred[3];
  __syncthreads();
  const float rinv = 1.0f / fmaxf(sbc[1], 1e-30f);

  if (inw) {
    bf16x8 o;
#pragma unroll
    for (int j = 0; j < 8; j++) o[j] = (bf16_t)(e[j] * rinv);
    *(bf16x8*)(r + base) = o;
  }
}

extern "C" void kernel_launch(void* const* d_in, const int* in_sizes, int n_in,
                              void* d_out, int out_size, void* d_ws, size_t ws_size,
                              hipStream_t stream) {
  const float* x  = (const float*)d_in[0];
  const float* Wq = (const float*)d_in[1];
  const float* Wk = (const float*)d_in[2];
  const float* Wv = (const float*)d_in[3];
  float* out = (float*)d_out;

  const int Bb = 4, S = 2048, D = 1024;
  const int M = Bb * S;  // 8192

  // ws (bf16 elems): Q | K | Vt | Wt(3*D*D) | Xb | V   = 90,177,536 B (proven fit)
  // Sc (Bb*S*S == 2*M*D) aliases [Xb|V], both dead before the scores gemm.
  bf16_t* ws = (bf16_t*)d_ws;
  bf16_t* Q   = ws;
  bf16_t* Kp  = Q  + (size_t)M * D;
  bf16_t* Vt  = Kp + (size_t)M * D;
  bf16_t* Wt  = Vt + (size_t)M * D;          // [3072][1024] stacked
  bf16_t* Xb  = Wt + 3 * (size_t)D * D;
  bf16_t* V   = Xb + (size_t)M * D;
  bf16_t* Sc  = Xb;

  const dim3 tb(32, 8);
  const dim3 blk(256);

  // 1) W fp32 -> bf16 transposed, stacked (one launch, z = which W)
  transpose_cvt3<<<dim3(D / 32, D / 32, 3), tb, 0, stream>>>(Wq, Wk, Wv, Wt, D);

  // 2) x -> bf16
  cvt_f32_bf16<<<dim3((M * D) / (256 * 8)), blk, 0, stream>>>(x, Xb, (long)M * D);

  // 3) fused projections: {Q,K,V} = Xb * Wt^T   (grid 24 x 64 = 1536 blocks)
  gemm_nt_bf16<bf16_t><<<dim3(3 * D / BN, M / BM, 1), blk, 0, stream>>>(
      Xb, Wt, Q, Kp, V, M, D, D, 0, 0, 0, 3);

  // 4) Vt per batch
  transpose16<<<dim3(D / 32, S / 32, Bb), tb, 0, stream>>>((const unsigned short*)V, (unsigned short*)Vt, S, D);

  // 5) scores Sc = Q*K^T per batch (upper-triangle tiles skipped; Xb/V dead)
  gemm_nt_bf16<bf16_t><<<dim3(S / BN, S / BM, Bb), blk, 0, stream>>>(
      Q, Kp, Sc, Sc, Sc, S, D, S, (long)S * D, (long)S * D, (long)S * S, 1);

  // 6) causal softmax in place
  softmax_causal<<<dim3(Bb * S), blk, 0, stream>>>(Sc, S);

  // 7) out(fp32) = P*V  (NT with Vt; K clamped causally)
  gemm_nt_bf16<float><<<dim3(D / BN, S / BM, Bb), blk, 0, stream>>>(
      Sc, Vt, out, out, out, S, S, D, (long)S * S, (long)D * S, (long)S * D, 2);
}

// Round 6
// 265.819 us; speedup vs baseline: 1.3209x; 1.0937x over previous
//
#include <hip/hip_runtime.h>
#include <hip/hip_bf16.h>

// CausalAttention: B=4, S=2048, d=1024, single head, causal. fp32 I/O, bf16 MFMA inside.
//
// R6: (1) BK 32 -> 64: 32 MFMA per barrier (AITER granularity, s02), half the
//         barrier drains; LDS 32 KB/block (5 blocks/CU cap).
//     (2) new XOR swizzle for 128B rows: LDS pos p of row r holds global chunk
//         p ^ (r&7); fragment reads hit all 32 banks 2-way (free, m136).
//     (3) heavy-first dispatch for triangular kernels (reverse y in modes 1/2).
//
// Pipeline:
//   1) Wq/Wk/Wv fp32 -> bf16 transposed, stacked Wt [3072][1024]  (one launch)
//   2) x fp32 -> bf16 Xb
//   3) {Q,K,V} = Xb * Wt^T  (one fused NT gemm, mode 3)
//   4) Vt = V^T per batch
//   5) Sc = Q*K^T per batch (skip tiles fully above diagonal, mode 1)
//   6) causal softmax rows of Sc in place (mask-before-scale == softmax(s/32))
//   7) out(fp32) = P*V  (NT with Vt; K clamped at rowBase+128, mode 2)

typedef __bf16 bf16_t;
typedef __bf16 bf16x8 __attribute__((ext_vector_type(8)));
typedef float f32x4 __attribute__((ext_vector_type(4)));

#define BM 128
#define BN 128
#define BK 64

__device__ __forceinline__ void load_lds16(const bf16_t* g, bf16_t* l) {
  __builtin_amdgcn_global_load_lds(
      (__attribute__((address_space(1))) void*)(void*)g,
      (__attribute__((address_space(3))) void*)l,
      16, 0, 0);
}

// C[m][n] = sum_k A[m][k]*B[n][k]  (A:[M][K], B:[N][K] row-major bf16)
// mode: 0 dense | 1 scores (skip tiles fully above diag) | 2 pv (clamp K at rowBase+BM)
//       3 fused qkv (block col / 1024 selects C0/C1/C2, ldc=1024)
template <typename OT>
__global__ __launch_bounds__(256)
void gemm_nt_bf16(const bf16_t* __restrict__ A, const bf16_t* __restrict__ B,
                  OT* __restrict__ C0, OT* __restrict__ C1, OT* __restrict__ C2,
                  int M, int K, int ldc,
                  long strideA, long strideB, long strideC, int mode)
{
  // heavy-first for triangular work: big rowBase dispatches first
  const int by = (mode == 1 || mode == 2) ? (gridDim.y - 1 - blockIdx.y) : blockIdx.y;
  const int rowBase = by * BM;
  const int colBase = blockIdx.x * BN;
  if (mode == 1 && colBase >= rowBase + BM) return;  // fully-masked score tile

  __shared__ __align__(16) bf16_t sA[BM * BK];   // [row][8 chunks of 16B], 16 KB
  __shared__ __align__(16) bf16_t sB[BN * BK];   // 16 KB

  A += (size_t)blockIdx.z * strideA;
  B += (size_t)blockIdx.z * strideB;

  const int tid  = threadIdx.x;
  const int wave = tid >> 6;
  const int lane = tid & 63;
  const int quad = lane >> 4;
  const int ln16 = lane & 15;

  const int wm = (wave & 1) * 64;   // wave's 64x64 subtile
  const int wn = (wave >> 1) * 64;

  // staging: wave stages rows [wave*32, wave*32+32), 4 instructions of 8 rows each.
  // lane ell -> local row r=ell>>3, LDS pos p=ell&7; fetch global chunk p^r (swizzle).
  const int sRow = wave * 32 + (lane >> 3);                 // +j*8 per instruction
  const int sCol = ((lane & 7) ^ (lane >> 3)) * 8;          // swizzled chunk * 8 elems
  bf16_t* ldsA = sA + wave * 2048;                          // wave*32 rows * 64
  bf16_t* ldsB = sB + wave * 2048;

  f32x4 acc[4][4] = {};

  const int Kend = (mode == 2) ? (K < rowBase + BM ? K : rowBase + BM) : K;

  const bf16_t* pA = A + (size_t)(rowBase + sRow) * K + sCol;
  const bf16_t* pB = B + (size_t)(colBase + sRow) * K + sCol;

  for (int k0 = 0; k0 < Kend; k0 += BK) {
#pragma unroll
    for (int j = 0; j < 4; j++) {
      load_lds16(pA + k0 + (size_t)(8 * j) * K, ldsA + j * 512);
      load_lds16(pB + k0 + (size_t)(8 * j) * K, ldsB + j * 512);
    }
    __syncthreads();   // drains vmcnt for all waves

#pragma unroll
    for (int kk = 0; kk < 2; kk++) {
      bf16x8 af[4], bfr[4];
#pragma unroll
      for (int mt = 0; mt < 4; mt++) {
        const int row = wm + mt * 16 + ln16;
        af[mt] = *(const bf16x8*)(sA + row * BK + (((kk * 4 + quad) ^ (row & 7)) * 8));
      }
#pragma unroll
      for (int nt = 0; nt < 4; nt++) {
        const int row = wn + nt * 16 + ln16;
        bfr[nt] = *(const bf16x8*)(sB + row * BK + (((kk * 4 + quad) ^ (row & 7)) * 8));
      }
#pragma unroll
      for (int mt = 0; mt < 4; mt++)
#pragma unroll
        for (int nt = 0; nt < 4; nt++)
          acc[mt][nt] = __builtin_amdgcn_mfma_f32_16x16x32_bf16(af[mt], bfr[nt], acc[mt][nt], 0, 0, 0);
    }
    __syncthreads();
  }

  // output target: mode 3 splits by 1024-col groups (uniform per block)
  OT* Cw = C0;
  int cb = colBase;
  if (mode == 3) {
    const int which = colBase >> 10;
    Cw = (which == 0) ? C0 : (which == 1) ? C1 : C2;
    cb = colBase & 1023;
  }
  Cw += (size_t)blockIdx.z * strideC;

  // epilogue: C/D layout col = lane&15, row = quad*4 + r  [measured m89/m91]
#pragma unroll
  for (int mt = 0; mt < 4; mt++) {
#pragma unroll
    for (int nt = 0; nt < 4; nt++) {
#pragma unroll
      for (int r = 0; r < 4; r++) {
        const int row = rowBase + wm + mt * 16 + quad * 4 + r;
        const int col = cb + wn + nt * 16 + ln16;
        Cw[(size_t)row * ldc + col] = (OT)acc[mt][nt][r];
      }
    }
  }
}

// three fp32 [D][D] -> bf16 transposed, stacked [3D][D]; z selects source
__global__ __launch_bounds__(256)
void transpose_cvt3(const float* __restrict__ w0, const float* __restrict__ w1,
                    const float* __restrict__ w2, bf16_t* __restrict__ out, int D)
{
  const float* in = (blockIdx.z == 0) ? w0 : (blockIdx.z == 1) ? w1 : w2;
  bf16_t* o = out + (size_t)blockIdx.z * D * D;
  __shared__ float tile[32][33];
  const int c0 = blockIdx.x * 32, r0 = blockIdx.y * 32;
  const int tx = threadIdx.x, ty = threadIdx.y;  // (32, 8)
#pragma unroll
  for (int i = 0; i < 32; i += 8)
    tile[ty + i][tx] = in[(size_t)(r0 + ty + i) * D + (c0 + tx)];
  __syncthreads();
#pragma unroll
  for (int i = 0; i < 32; i += 8)
    o[(size_t)(c0 + ty + i) * D + (r0 + tx)] = (bf16_t)tile[tx][ty + i];
}

// bf16 [R][C] -> bf16 transposed [C][R]; batched via blockIdx.z
__global__ __launch_bounds__(256)
void transpose16(const unsigned short* __restrict__ in, unsigned short* __restrict__ out,
                 int R, int C)
{
  __shared__ unsigned short tile[32][33];
  const size_t bo = (size_t)blockIdx.z * R * C;
  const int c0 = blockIdx.x * 32, r0 = blockIdx.y * 32;
  const int tx = threadIdx.x, ty = threadIdx.y;  // (32, 8)
#pragma unroll
  for (int i = 0; i < 32; i += 8)
    tile[ty + i][tx] = in[bo + (size_t)(r0 + ty + i) * C + (c0 + tx)];
  __syncthreads();
#pragma unroll
  for (int i = 0; i < 32; i += 8)
    out[bo + (size_t)(c0 + ty + i) * R + (r0 + tx)] = tile[tx][ty + i];
}

// fp32 -> bf16 elementwise, 8/thread, vector load+store
__global__ __launch_bounds__(256)
void cvt_f32_bf16(const float* __restrict__ in, bf16_t* __restrict__ out, long n)
{
  long i = ((long)blockIdx.x * 256 + threadIdx.x) * 8;
  if (i + 7 < n) {
    float4 a = *(const float4*)(in + i);
    float4 b = *(const float4*)(in + i + 4);
    bf16x8 o;
    o[0] = (bf16_t)a.x; o[1] = (bf16_t)a.y; o[2] = (bf16_t)a.z; o[3] = (bf16_t)a.w;
    o[4] = (bf16_t)b.x; o[5] = (bf16_t)b.y; o[6] = (bf16_t)b.z; o[7] = (bf16_t)b.w;
    *(bf16x8*)(out + i) = o;
  }
}

// In-place causal softmax on bf16 scores [B*S][S]; row q valid cols 0..q.
// One bf16x8 per thread (S=2048=256*8); writes only to the causal 128-block edge.
__global__ __launch_bounds__(256)
void softmax_causal(bf16_t* __restrict__ sc, int S)
{
  const int row = blockIdx.x;        // b*S + q
  const int q   = row & (S - 1);
  bf16_t* r = sc + (size_t)row * S;
  const int tid = threadIdx.x;
  const int nvalid = q + 1;
  const int wend = ((q >> 7) + 1) << 7;   // 128-aligned write end
  constexpr float inv = 0.03125f;         // 1/sqrt(1024)
  const int base = tid * 8;

  __shared__ float sred[4];
  __shared__ float sbc[2];

  float v[8];
  const bool inw = base < wend;
  if (inw) {
    bf16x8 d = *(const bf16x8*)(r + base);
#pragma unroll
    for (int j = 0; j < 8; j++) v[j] = (float)d[j];
  }

  float lmax = -3.0e38f;
  if (base < nvalid) {
#pragma unroll
    for (int j = 0; j < 8; j++) if (base + j < nvalid) lmax = fmaxf(lmax, v[j]);
  }
#pragma unroll
  for (int off = 32; off > 0; off >>= 1) lmax = fmaxf(lmax, __shfl_down(lmax, off, 64));
  if ((tid & 63) == 0) sred[tid >> 6] = lmax;
  __syncthreads();
  if (tid == 0) sbc[0] = fmaxf(fmaxf(sred[0], sred[1]), fmaxf(sred[2], sred[3]));
  __syncthreads();
  const float rmax = sbc[0];

  float e[8];
  float lsum = 0.0f;
#pragma unroll
  for (int j = 0; j < 8; j++) {
    if (base + j < nvalid) { e[j] = __expf((v[j] - rmax) * inv); lsum += e[j]; }
    else e[j] = 0.0f;
  }
#pragma unroll
  for (int off = 32; off > 0; off >>= 1) lsum += __shfl_down(lsum, off, 64);
  if ((tid & 63) == 0) sred[tid >> 6] = lsum;
  __syncthreads();
  if (tid == 0) sbc[1] = sred[0] + sred[1] + sred[2] + sred[3];
  __syncthreads();
  const float rinv = 1.0f / fmaxf(sbc[1], 1e-30f);

  if (inw) {
    bf16x8 o;
#pragma unroll
    for (int j = 0; j < 8; j++) o[j] = (bf16_t)(e[j] * rinv);
    *(bf16x8*)(r + base) = o;
  }
}

extern "C" void kernel_launch(void* const* d_in, const int* in_sizes, int n_in,
                              void* d_out, int out_size, void* d_ws, size_t ws_size,
                              hipStream_t stream) {
  const float* x  = (const float*)d_in[0];
  const float* Wq = (const float*)d_in[1];
  const float* Wk = (const float*)d_in[2];
  const float* Wv = (const float*)d_in[3];
  float* out = (float*)d_out;

  const int Bb = 4, S = 2048, D = 1024;
  const int M = Bb * S;  // 8192

  // ws (bf16 elems): Q | K | Vt | Wt(3*D*D) | Xb | V   = 90,177,536 B (proven fit)
  // Sc (Bb*S*S == 2*M*D) aliases [Xb|V], both dead before the scores gemm.
  bf16_t* ws = (bf16_t*)d_ws;
  bf16_t* Q   = ws;
  bf16_t* Kp  = Q  + (size_t)M * D;
  bf16_t* Vt  = Kp + (size_t)M * D;
  bf16_t* Wt  = Vt + (size_t)M * D;          // [3072][1024] stacked
  bf16_t* Xb  = Wt + 3 * (size_t)D * D;
  bf16_t* V   = Xb + (size_t)M * D;
  bf16_t* Sc  = Xb;

  const dim3 tb(32, 8);
  const dim3 blk(256);

  // 1) W fp32 -> bf16 transposed, stacked (one launch, z = which W)
  transpose_cvt3<<<dim3(D / 32, D / 32, 3), tb, 0, stream>>>(Wq, Wk, Wv, Wt, D);

  // 2) x -> bf16
  cvt_f32_bf16<<<dim3((M * D) / (256 * 8)), blk, 0, stream>>>(x, Xb, (long)M * D);

  // 3) fused projections: {Q,K,V} = Xb * Wt^T   (grid 24 x 64 = 1536 blocks)
  gemm_nt_bf16<bf16_t><<<dim3(3 * D / BN, M / BM, 1), blk, 0, stream>>>(
      Xb, Wt, Q, Kp, V, M, D, D, 0, 0, 0, 3);

  // 4) Vt per batch
  transpose16<<<dim3(D / 32, S / 32, Bb), tb, 0, stream>>>((const unsigned short*)V, (unsigned short*)Vt, S, D);

  // 5) scores Sc = Q*K^T per batch (upper-triangle tiles skipped; Xb/V dead)
  gemm_nt_bf16<bf16_t><<<dim3(S / BN, S / BM, Bb), blk, 0, stream>>>(
      Q, Kp, Sc, Sc, Sc, S, D, S, (long)S * D, (long)S * D, (long)S * S, 1);

  // 6) causal softmax in place
  softmax_causal<<<dim3(Bb * S), blk, 0, stream>>>(Sc, S);

  // 7) out(fp32) = P*V  (NT with Vt; K clamped causally)
  gemm_nt_bf16<float><<<dim3(D / BN, S / BM, Bb), blk, 0, stream>>>(
      Sc, Vt, out, out, out, S, S, D, (long)S * S, (long)D * S, (long)S * D, 2);
}

// Round 7
// 248.369 us; speedup vs baseline: 1.4137x; 1.0703x over previous
//
#include <hip/hip_runtime.h>
#include <hip/hip_bf16.h>

// CausalAttention: B=4, S=2048, d=1024, single head, causal. fp32 I/O, bf16 MFMA inside.
//
// R7: (1) templated GEMM tile; QKV + scores use 256x128 / 8-wave blocks ->
//         grid 768 = exactly 3 blocks/CU * 256 CU (48 KB LDS), zero scheduling tail;
//     (2) softmax kernel ELIMINATED: scores epilogue does causal mask + exp(s/32)
//         (fp32, no max pass needed -- args bounded) + per-row sums via shfl+atomicAdd;
//         PV epilogue scales by 1/rowsum. Saves a dispatch + ~34 MB HBM traffic;
//     (3) rowsum (32 KB) reuses the Wt region (dead after QKV).
//
// Pipeline:
//   1) Wq/Wk/Wv fp32 -> bf16 transposed, stacked Wt [3072][1024]
//   2) x fp32 -> bf16 Xb
//   3) {Q,K,V} = Xb * Wt^T       (mode 3, 256x128 tiles)
//   4) zero rowsum; Vt = V^T per batch
//   5) E = masked-exp(Q*K^T/32), rowsum accumulated   (mode 1, 256x128 tiles)
//   6) out(fp32) = (E * V) / rowsum                   (mode 2, 128x128, K clamped)

typedef __bf16 bf16_t;
typedef __bf16 bf16x8 __attribute__((ext_vector_type(8)));
typedef float f32x4 __attribute__((ext_vector_type(4)));

__device__ __forceinline__ void load_lds16(const bf16_t* g, bf16_t* l) {
  __builtin_amdgcn_global_load_lds(
      (__attribute__((address_space(1))) void*)(void*)g,
      (__attribute__((address_space(3))) void*)l,
      16, 0, 0);
}

// C[m][n] = sum_k A[m][k]*B[n][k]  (A:[M][K], B:[N][K] row-major bf16)
// mode: 0 dense | 1 scores: skip tiles above diag, epilogue mask+exp+rowsum
//       2 pv: clamp K at rowBase+BMv, epilogue scale by 1/rowsum | 3 fused qkv split
// LDS swizzle: 16B chunk position p of row r holds global chunk p ^ (r&7);
// fragment reads then hit all 32 banks 2-way (free). Staging lane l fetches
// chunk (l&7)^(l>>3) -- row-within-8 group invariant, so one offset serves all j.
template <int BMv, int BNv, int NW, typename OT>
__global__ __launch_bounds__(NW * 64)
void gemm_nt_bf16(const bf16_t* __restrict__ A, const bf16_t* __restrict__ B,
                  OT* __restrict__ C0, OT* __restrict__ C1, OT* __restrict__ C2,
                  float* __restrict__ RS,
                  int M, int K, int ldc,
                  long strideA, long strideB, long strideC, int mode)
{
  constexpr int MW = BMv / 64;       // wave grid: MW x (NW/MW)
  constexpr int RA = BMv / NW;       // rows staged per wave (A)
  constexpr int RB = BNv / NW;       // rows staged per wave (B)

  const int by = (mode == 1 || mode == 2) ? (gridDim.y - 1 - blockIdx.y) : blockIdx.y;
  const int rowBase = by * BMv;
  const int colBase = blockIdx.x * BNv;
  if (mode == 1 && colBase >= rowBase + BMv) return;  // fully-masked score tile

  __shared__ __align__(16) bf16_t sA[BMv * 64];
  __shared__ __align__(16) bf16_t sB[BNv * 64];

  A += (size_t)blockIdx.z * strideA;
  B += (size_t)blockIdx.z * strideB;
  float* rs_b = RS + (size_t)blockIdx.z * 2048;

  const int tid  = threadIdx.x;
  const int wave = tid >> 6;
  const int lane = tid & 63;
  const int quad = lane >> 4;
  const int ln16 = lane & 15;

  const int wm = (wave % MW) * 64;
  const int wn = (wave / MW) * 64;

  const int rA = lane >> 3;                       // 0..7 row-in-group
  const int sColOff = ((lane & 7) ^ rA) * 8;      // swizzled chunk offset (elems)
  const bf16_t* pA = A + (size_t)(rowBase + wave * RA + rA) * K + sColOff;
  const bf16_t* pB = B + (size_t)(colBase + wave * RB + rA) * K + sColOff;
  bf16_t* ldsA = sA + wave * RA * 64;
  bf16_t* ldsB = sB + wave * RB * 64;

  f32x4 acc[4][4] = {};

  const int Kend = (mode == 2) ? (K < rowBase + BMv ? K : rowBase + BMv) : K;

  for (int k0 = 0; k0 < Kend; k0 += 64) {
#pragma unroll
    for (int j = 0; j < RA / 8; j++)
      load_lds16(pA + k0 + (size_t)(8 * j) * K, ldsA + j * 512);
#pragma unroll
    for (int j = 0; j < RB / 8; j++)
      load_lds16(pB + k0 + (size_t)(8 * j) * K, ldsB + j * 512);
    __syncthreads();   // drains vmcnt for all waves

#pragma unroll
    for (int kk = 0; kk < 2; kk++) {
      bf16x8 af[4], bfr[4];
#pragma unroll
      for (int mt = 0; mt < 4; mt++) {
        const int row = wm + mt * 16 + ln16;
        af[mt] = *(const bf16x8*)(sA + row * 64 + (((kk * 4 + quad) ^ (row & 7)) * 8));
      }
#pragma unroll
      for (int nt = 0; nt < 4; nt++) {
        const int row = wn + nt * 16 + ln16;
        bfr[nt] = *(const bf16x8*)(sB + row * 64 + (((kk * 4 + quad) ^ (row & 7)) * 8));
      }
#pragma unroll
      for (int mt = 0; mt < 4; mt++)
#pragma unroll
        for (int nt = 0; nt < 4; nt++)
          acc[mt][nt] = __builtin_amdgcn_mfma_f32_16x16x32_bf16(af[mt], bfr[nt], acc[mt][nt], 0, 0, 0);
    }
    __syncthreads();
  }

  // output target: mode 3 splits by 1024-col groups (uniform per block)
  OT* Cw = C0;
  int cb = colBase;
  if (mode == 3) {
    const int which = colBase >> 10;
    Cw = (which == 0) ? C0 : (which == 1) ? C1 : C2;
    cb = colBase & 1023;
  }
  Cw += (size_t)blockIdx.z * strideC;

  // epilogue: C/D layout col = lane&15, row = quad*4 + r  [measured m89/m91]
#pragma unroll
  for (int mt = 0; mt < 4; mt++) {
#pragma unroll
    for (int r = 0; r < 4; r++) {
      const int row = rowBase + wm + mt * 16 + quad * 4 + r;
      float rsum = 0.0f;
      float rinv = 1.0f;
      if (mode == 2) rinv = 1.0f / rs_b[row];
#pragma unroll
      for (int nt = 0; nt < 4; nt++) {
        const int col = cb + wn + nt * 16 + ln16;
        float v = acc[mt][nt][r];
        if (mode == 1) {
          const float e = (col <= row) ? __expf(v * 0.03125f) : 0.0f;  // s/sqrt(1024)
          rsum += e;
          v = e;
        } else if (mode == 2) {
          v *= rinv;
        }
        Cw[(size_t)row * ldc + col] = (OT)v;
      }
      if (mode == 1) {
        rsum += __shfl_xor(rsum, 1, 64);
        rsum += __shfl_xor(rsum, 2, 64);
        rsum += __shfl_xor(rsum, 4, 64);
        rsum += __shfl_xor(rsum, 8, 64);
        if (ln16 == 0) atomicAdd(rs_b + row, rsum);
      }
    }
  }
}

// three fp32 [D][D] -> bf16 transposed, stacked [3D][D]; z selects source
__global__ __launch_bounds__(256)
void transpose_cvt3(const float* __restrict__ w0, const float* __restrict__ w1,
                    const float* __restrict__ w2, bf16_t* __restrict__ out, int D)
{
  const float* in = (blockIdx.z == 0) ? w0 : (blockIdx.z == 1) ? w1 : w2;
  bf16_t* o = out + (size_t)blockIdx.z * D * D;
  __shared__ float tile[32][33];
  const int c0 = blockIdx.x * 32, r0 = blockIdx.y * 32;
  const int tx = threadIdx.x, ty = threadIdx.y;  // (32, 8)
#pragma unroll
  for (int i = 0; i < 32; i += 8)
    tile[ty + i][tx] = in[(size_t)(r0 + ty + i) * D + (c0 + tx)];
  __syncthreads();
#pragma unroll
  for (int i = 0; i < 32; i += 8)
    o[(size_t)(c0 + ty + i) * D + (r0 + tx)] = (bf16_t)tile[tx][ty + i];
}

// bf16 [R][C] -> bf16 transposed [C][R]; batched via blockIdx.z
__global__ __launch_bounds__(256)
void transpose16(const unsigned short* __restrict__ in, unsigned short* __restrict__ out,
                 int R, int C)
{
  __shared__ unsigned short tile[32][33];
  const size_t bo = (size_t)blockIdx.z * R * C;
  const int c0 = blockIdx.x * 32, r0 = blockIdx.y * 32;
  const int tx = threadIdx.x, ty = threadIdx.y;  // (32, 8)
#pragma unroll
  for (int i = 0; i < 32; i += 8)
    tile[ty + i][tx] = in[bo + (size_t)(r0 + ty + i) * C + (c0 + tx)];
  __syncthreads();
#pragma unroll
  for (int i = 0; i < 32; i += 8)
    out[bo + (size_t)(c0 + ty + i) * R + (r0 + tx)] = tile[tx][ty + i];
}

// fp32 -> bf16 elementwise, 8/thread, vector load+store
__global__ __launch_bounds__(256)
void cvt_f32_bf16(const float* __restrict__ in, bf16_t* __restrict__ out, long n)
{
  long i = ((long)blockIdx.x * 256 + threadIdx.x) * 8;
  if (i + 7 < n) {
    float4 a = *(const float4*)(in + i);
    float4 b = *(const float4*)(in + i + 4);
    bf16x8 o;
    o[0] = (bf16_t)a.x; o[1] = (bf16_t)a.y; o[2] = (bf16_t)a.z; o[3] = (bf16_t)a.w;
    o[4] = (bf16_t)b.x; o[5] = (bf16_t)b.y; o[6] = (bf16_t)b.z; o[7] = (bf16_t)b.w;
    *(bf16x8*)(out + i) = o;
  }
}

__global__ __launch_bounds__(256)
void zero_f32(float* __restrict__ p, int n)
{
  const int i = blockIdx.x * 256 + threadIdx.x;
  if (i < n) p[i] = 0.0f;
}

extern "C" void kernel_launch(void* const* d_in, const int* in_sizes, int n_in,
                              void* d_out, int out_size, void* d_ws, size_t ws_size,
                              hipStream_t stream) {
  const float* x  = (const float*)d_in[0];
  const float* Wq = (const float*)d_in[1];
  const float* Wk = (const float*)d_in[2];
  const float* Wv = (const float*)d_in[3];
  float* out = (float*)d_out;

  const int Bb = 4, S = 2048, D = 1024;
  const int M = Bb * S;  // 8192

  // ws (bf16 elems): Q | K | Vt | Wt(3*D*D) | Xb | V   = 90,177,536 B (proven fit)
  // Sc (Bb*S*S == 2*M*D) aliases [Xb|V]; rowsum (32 KB f32) reuses Wt (dead post-QKV).
  bf16_t* ws = (bf16_t*)d_ws;
  bf16_t* Q   = ws;
  bf16_t* Kp  = Q  + (size_t)M * D;
  bf16_t* Vt  = Kp + (size_t)M * D;
  bf16_t* Wt  = Vt + (size_t)M * D;          // [3072][1024] stacked
  bf16_t* Xb  = Wt + 3 * (size_t)D * D;
  bf16_t* V   = Xb + (size_t)M * D;
  bf16_t* Sc  = Xb;
  float*  rowsum = (float*)Wt;               // Bb*S floats

  const dim3 tb(32, 8);

  // 1) W fp32 -> bf16 transposed, stacked
  transpose_cvt3<<<dim3(D / 32, D / 32, 3), tb, 0, stream>>>(Wq, Wk, Wv, Wt, D);

  // 2) x -> bf16
  cvt_f32_bf16<<<dim3((M * D) / (256 * 8)), dim3(256), 0, stream>>>(x, Xb, (long)M * D);

  // 3) fused projections: {Q,K,V} = Xb * Wt^T   (grid 24 x 32 = 768 = 3/CU exactly)
  gemm_nt_bf16<256, 128, 8, bf16_t><<<dim3(3 * D / 128, M / 256, 1), dim3(512), 0, stream>>>(
      Xb, Wt, Q, Kp, V, rowsum, M, D, D, 0, 0, 0, 3);

  // 4) zero rowsum (Wt dead now); Vt per batch
  zero_f32<<<dim3(M / 256), dim3(256), 0, stream>>>(rowsum, M);
  transpose16<<<dim3(D / 32, S / 32, Bb), tb, 0, stream>>>((const unsigned short*)V, (unsigned short*)Vt, S, D);

  // 5) E = masked-exp(Q*K^T/32) + rowsum   (grid 16 x 8 x 4, 288 active blocks)
  gemm_nt_bf16<256, 128, 8, bf16_t><<<dim3(S / 128, S / 256, Bb), dim3(512), 0, stream>>>(
      Q, Kp, Sc, Sc, Sc, rowsum, S, D, S, (long)S * D, (long)S * D, (long)S * S, 1);

  // 6) out(fp32) = (E*V)/rowsum  (NT with Vt; K clamped causally)
  gemm_nt_bf16<128, 128, 4, float><<<dim3(D / 128, S / 128, Bb), dim3(256), 0, stream>>>(
      Sc, Vt, out, out, out, rowsum, S, S, D, (long)S * S, (long)D * S, (long)S * D, 2);
}

// Round 8
// 238.165 us; speedup vs baseline: 1.4743x; 1.0428x over previous
//
#include <hip/hip_runtime.h>
#include <hip/hip_bf16.h>

// CausalAttention: B=4, S=2048, d=1024, single head, causal. fp32 I/O, bf16 MFMA inside.
//
// R8: XCD-aware block remap in the GEMM. flat_block_id % 8 = XCD (m09 round-robin).
//     All column-blocks sharing an A row-panel (y,z) are pinned to ONE XCD, so the
//     panel (512 KB; 4 panels = 2 MB per XCD) stays in that XCD's private 4 MB L2
//     and is fetched from HBM/LLC once per XCD instead of once per block.
//     R7 diagnosis: 576 MB of redundant A-panel traffic through LLC ~= the whole
//     66.6 us QKV dispatch (FETCH 73.8 MB vs 22 MB compulsory; 50% SIMD wait).
//
// Pipeline:
//   1) Wq/Wk/Wv fp32 -> bf16 transposed, stacked Wt [3072][1024]
//   2) x fp32 -> bf16 Xb
//   3) {Q,K,V} = Xb * Wt^T       (mode 3, 256x128 tiles, 8 waves)
//   4) zero rowsum; Vt = V^T per batch
//   5) E = masked-exp(Q*K^T/32), rowsum accumulated   (mode 1, 256x128)
//   6) out(fp32) = (E * V) / rowsum                   (mode 2, 128x128, K clamped)

typedef __bf16 bf16_t;
typedef __bf16 bf16x8 __attribute__((ext_vector_type(8)));
typedef float f32x4 __attribute__((ext_vector_type(4)));

__device__ __forceinline__ void load_lds16(const bf16_t* g, bf16_t* l) {
  __builtin_amdgcn_global_load_lds(
      (__attribute__((address_space(1))) void*)(void*)g,
      (__attribute__((address_space(3))) void*)l,
      16, 0, 0);
}

// C[m][n] = sum_k A[m][k]*B[n][k]  (A:[M][K], B:[N][K] row-major bf16)
// mode: 1 scores: skip tiles above diag, epilogue mask+exp+rowsum
//       2 pv: clamp K at rowBase+BMv, epilogue scale by 1/rowsum | 3 fused qkv split
// LDS swizzle: 16B chunk position p of row r holds global chunk p ^ (r&7);
// fragment reads hit all 32 banks 2-way (free, m136). Conflicts measured 0 (R5-R7).
template <int BMv, int BNv, int NW, typename OT>
__global__ __launch_bounds__(NW * 64)
void gemm_nt_bf16(const bf16_t* __restrict__ A, const bf16_t* __restrict__ B,
                  OT* __restrict__ C0, OT* __restrict__ C1, OT* __restrict__ C2,
                  float* __restrict__ RS,
                  int M, int K, int ldc,
                  long strideA, long strideB, long strideC, int mode)
{
  constexpr int MW = BMv / 64;       // wave grid: MW x (NW/MW)
  constexpr int RA = BMv / NW;       // rows staged per wave (A)
  constexpr int RB = BNv / NW;       // rows staged per wave (B)

  // XCD-aware remap: pin all x-blocks of an A-panel (y,z) to one XCD.
  // Requires (gridDim.y*gridDim.z) % 8 == 0 -- true for all launches here.
  const int gx = gridDim.x, gy = gridDim.y;
  const int NP = gy * gridDim.z;
  const int P  = NP >> 3;                         // panels per XCD
  const int flat = blockIdx.x + gx * (blockIdx.y + gy * blockIdx.z);
  const int xcd  = flat & 7;
  const int i    = flat >> 3;
  const int pan  = xcd * P + (i % P);
  const int bx   = i / P;
  int by = pan % gy;
  const int bz   = pan / gy;
  if (mode == 1 || mode == 2) by = gy - 1 - by;   // heavy-first

  const int rowBase = by * BMv;
  const int colBase = bx * BNv;
  if (mode == 1 && colBase >= rowBase + BMv) return;  // fully-masked score tile

  __shared__ __align__(16) bf16_t sA[BMv * 64];
  __shared__ __align__(16) bf16_t sB[BNv * 64];

  A += (size_t)bz * strideA;
  B += (size_t)bz * strideB;
  float* rs_b = RS + (size_t)bz * 2048;

  const int tid  = threadIdx.x;
  const int wave = tid >> 6;
  const int lane = tid & 63;
  const int quad = lane >> 4;
  const int ln16 = lane & 15;

  const int wm = (wave % MW) * 64;
  const int wn = (wave / MW) * 64;

  const int rA = lane >> 3;                       // 0..7 row-in-group
  const int sColOff = ((lane & 7) ^ rA) * 8;      // swizzled chunk offset (elems)
  const bf16_t* pA = A + (size_t)(rowBase + wave * RA + rA) * K + sColOff;
  const bf16_t* pB = B + (size_t)(colBase + wave * RB + rA) * K + sColOff;
  bf16_t* ldsA = sA + wave * RA * 64;
  bf16_t* ldsB = sB + wave * RB * 64;

  f32x4 acc[4][4] = {};

  const int Kend = (mode == 2) ? (K < rowBase + BMv ? K : rowBase + BMv) : K;

  for (int k0 = 0; k0 < Kend; k0 += 64) {
#pragma unroll
    for (int j = 0; j < RA / 8; j++)
      load_lds16(pA + k0 + (size_t)(8 * j) * K, ldsA + j * 512);
#pragma unroll
    for (int j = 0; j < RB / 8; j++)
      load_lds16(pB + k0 + (size_t)(8 * j) * K, ldsB + j * 512);
    __syncthreads();   // drains vmcnt for all waves

#pragma unroll
    for (int kk = 0; kk < 2; kk++) {
      bf16x8 af[4], bfr[4];
#pragma unroll
      for (int mt = 0; mt < 4; mt++) {
        const int row = wm + mt * 16 + ln16;
        af[mt] = *(const bf16x8*)(sA + row * 64 + (((kk * 4 + quad) ^ (row & 7)) * 8));
      }
#pragma unroll
      for (int nt = 0; nt < 4; nt++) {
        const int row = wn + nt * 16 + ln16;
        bfr[nt] = *(const bf16x8*)(sB + row * 64 + (((kk * 4 + quad) ^ (row & 7)) * 8));
      }
#pragma unroll
      for (int mt = 0; mt < 4; mt++)
#pragma unroll
        for (int nt = 0; nt < 4; nt++)
          acc[mt][nt] = __builtin_amdgcn_mfma_f32_16x16x32_bf16(af[mt], bfr[nt], acc[mt][nt], 0, 0, 0);
    }
    __syncthreads();
  }

  // output target: mode 3 splits by 1024-col groups (uniform per block)
  OT* Cw = C0;
  int cb = colBase;
  if (mode == 3) {
    const int which = colBase >> 10;
    Cw = (which == 0) ? C0 : (which == 1) ? C1 : C2;
    cb = colBase & 1023;
  }
  Cw += (size_t)bz * strideC;

  // epilogue: C/D layout col = lane&15, row = quad*4 + r  [measured m89/m91]
#pragma unroll
  for (int mt = 0; mt < 4; mt++) {
#pragma unroll
    for (int r = 0; r < 4; r++) {
      const int row = rowBase + wm + mt * 16 + quad * 4 + r;
      float rsum = 0.0f;
      float rinv = 1.0f;
      if (mode == 2) rinv = 1.0f / rs_b[row];
#pragma unroll
      for (int nt = 0; nt < 4; nt++) {
        const int col = cb + wn + nt * 16 + ln16;
        float v = acc[mt][nt][r];
        if (mode == 1) {
          const float e = (col <= row) ? __expf(v * 0.03125f) : 0.0f;  // s/sqrt(1024)
          rsum += e;
          v = e;
        } else if (mode == 2) {
          v *= rinv;
        }
        Cw[(size_t)row * ldc + col] = (OT)v;
      }
      if (mode == 1) {
        rsum += __shfl_xor(rsum, 1, 64);
        rsum += __shfl_xor(rsum, 2, 64);
        rsum += __shfl_xor(rsum, 4, 64);
        rsum += __shfl_xor(rsum, 8, 64);
        if (ln16 == 0) atomicAdd(rs_b + row, rsum);
      }
    }
  }
}

// three fp32 [D][D] -> bf16 transposed, stacked [3D][D]; z selects source
__global__ __launch_bounds__(256)
void transpose_cvt3(const float* __restrict__ w0, const float* __restrict__ w1,
                    const float* __restrict__ w2, bf16_t* __restrict__ out, int D)
{
  const float* in = (blockIdx.z == 0) ? w0 : (blockIdx.z == 1) ? w1 : w2;
  bf16_t* o = out + (size_t)blockIdx.z * D * D;
  __shared__ float tile[32][33];
  const int c0 = blockIdx.x * 32, r0 = blockIdx.y * 32;
  const int tx = threadIdx.x, ty = threadIdx.y;  // (32, 8)
#pragma unroll
  for (int i = 0; i < 32; i += 8)
    tile[ty + i][tx] = in[(size_t)(r0 + ty + i) * D + (c0 + tx)];
  __syncthreads();
#pragma unroll
  for (int i = 0; i < 32; i += 8)
    o[(size_t)(c0 + ty + i) * D + (r0 + tx)] = (bf16_t)tile[tx][ty + i];
}

// bf16 [R][C] -> bf16 transposed [C][R]; batched via blockIdx.z
__global__ __launch_bounds__(256)
void transpose16(const unsigned short* __restrict__ in, unsigned short* __restrict__ out,
                 int R, int C)
{
  __shared__ unsigned short tile[32][33];
  const size_t bo = (size_t)blockIdx.z * R * C;
  const int c0 = blockIdx.x * 32, r0 = blockIdx.y * 32;
  const int tx = threadIdx.x, ty = threadIdx.y;  // (32, 8)
#pragma unroll
  for (int i = 0; i < 32; i += 8)
    tile[ty + i][tx] = in[bo + (size_t)(r0 + ty + i) * C + (c0 + tx)];
  __syncthreads();
#pragma unroll
  for (int i = 0; i < 32; i += 8)
    out[bo + (size_t)(c0 + ty + i) * R + (r0 + tx)] = tile[tx][ty + i];
}

// fp32 -> bf16 elementwise, 8/thread, vector load+store
__global__ __launch_bounds__(256)
void cvt_f32_bf16(const float* __restrict__ in, bf16_t* __restrict__ out, long n)
{
  long i = ((long)blockIdx.x * 256 + threadIdx.x) * 8;
  if (i + 7 < n) {
    float4 a = *(const float4*)(in + i);
    float4 b = *(const float4*)(in + i + 4);
    bf16x8 o;
    o[0] = (bf16_t)a.x; o[1] = (bf16_t)a.y; o[2] = (bf16_t)a.z; o[3] = (bf16_t)a.w;
    o[4] = (bf16_t)b.x; o[5] = (bf16_t)b.y; o[6] = (bf16_t)b.z; o[7] = (bf16_t)b.w;
    *(bf16x8*)(out + i) = o;
  }
}

__global__ __launch_bounds__(256)
void zero_f32(float* __restrict__ p, int n)
{
  const int i = blockIdx.x * 256 + threadIdx.x;
  if (i < n) p[i] = 0.0f;
}

extern "C" void kernel_launch(void* const* d_in, const int* in_sizes, int n_in,
                              void* d_out, int out_size, void* d_ws, size_t ws_size,
                              hipStream_t stream) {
  const float* x  = (const float*)d_in[0];
  const float* Wq = (const float*)d_in[1];
  const float* Wk = (const float*)d_in[2];
  const float* Wv = (const float*)d_in[3];
  float* out = (float*)d_out;

  const int Bb = 4, S = 2048, D = 1024;
  const int M = Bb * S;  // 8192

  // ws (bf16 elems): Q | K | Vt | Wt(3*D*D) | Xb | V   = 90,177,536 B (proven fit)
  // Sc (Bb*S*S == 2*M*D) aliases [Xb|V]; rowsum (32 KB f32) reuses Wt (dead post-QKV).
  bf16_t* ws = (bf16_t*)d_ws;
  bf16_t* Q   = ws;
  bf16_t* Kp  = Q  + (size_t)M * D;
  bf16_t* Vt  = Kp + (size_t)M * D;
  bf16_t* Wt  = Vt + (size_t)M * D;          // [3072][1024] stacked
  bf16_t* Xb  = Wt + 3 * (size_t)D * D;
  bf16_t* V   = Xb + (size_t)M * D;
  bf16_t* Sc  = Xb;
  float*  rowsum = (float*)Wt;               // Bb*S floats

  const dim3 tb(32, 8);

  // 1) W fp32 -> bf16 transposed, stacked
  transpose_cvt3<<<dim3(D / 32, D / 32, 3), tb, 0, stream>>>(Wq, Wk, Wv, Wt, D);

  // 2) x -> bf16
  cvt_f32_bf16<<<dim3((M * D) / (256 * 8)), dim3(256), 0, stream>>>(x, Xb, (long)M * D);

  // 3) fused projections: {Q,K,V} = Xb * Wt^T  (grid 24 x 32; 32 panels -> 4/XCD)
  gemm_nt_bf16<256, 128, 8, bf16_t><<<dim3(3 * D / 128, M / 256, 1), dim3(512), 0, stream>>>(
      Xb, Wt, Q, Kp, V, rowsum, M, D, D, 0, 0, 0, 3);

  // 4) zero rowsum (Wt dead now); Vt per batch
  zero_f32<<<dim3(M / 256), dim3(256), 0, stream>>>(rowsum, M);
  transpose16<<<dim3(D / 32, S / 32, Bb), tb, 0, stream>>>((const unsigned short*)V, (unsigned short*)Vt, S, D);

  // 5) E = masked-exp(Q*K^T/32) + rowsum  (grid 16 x 8 x 4; 32 panels -> 4/XCD)
  gemm_nt_bf16<256, 128, 8, bf16_t><<<dim3(S / 128, S / 256, Bb), dim3(512), 0, stream>>>(
      Q, Kp, Sc, Sc, Sc, rowsum, S, D, S, (long)S * D, (long)S * D, (long)S * S, 1);

  // 6) out(fp32) = (E*V)/rowsum  (grid 8 x 16 x 4; 64 panels -> 8/XCD)
  gemm_nt_bf16<128, 128, 4, float><<<dim3(D / 128, S / 128, Bb), dim3(256), 0, stream>>>(
      Sc, Vt, out, out, out, rowsum, S, S, D, (long)S * S, (long)D * S, (long)S * D, 2);
}